// Round 1
// baseline (442.617 us; speedup 1.0000x reference)
//
#include <hip/hip_runtime.h>
#include <math.h>

#define B_ 128
#define D_ 128
#define Q_ 256
#define L_ 1024

// ---------------------------------------------------------------------------
// K1: S_T[b][q][l] = sum_d query[b][d][q] * ctx[b][d][l]
// TN GEMM: K=d is the slow dim of both operands -> direct (no-transpose) LDS
// staging. Tile 128(q) x 128(l) x 16(k), 256 threads, 8x8 per thread
// (2x2 blocks of 4x4, halves at +64 to keep LDS reads 2-way-conflict max).
// grid (L/128, Q/128, B)
// ---------------------------------------------------------------------------
__global__ __launch_bounds__(256) void k1_scores(
    const float* __restrict__ query, const float* __restrict__ ctx,
    float* __restrict__ S) {
  __shared__ float As[16][128];  // [k][q]
  __shared__ float Bs[16][128];  // [k][l]
  const int b  = blockIdx.z;
  const int q0 = blockIdx.y * 128;
  const int l0 = blockIdx.x * 128;
  const int tid = threadIdx.x;
  const int tx = tid & 15, ty = tid >> 4;

  const float* Ab = query + (size_t)b * D_ * Q_;
  const float* Bb = ctx   + (size_t)b * D_ * L_;

  float acc[2][2][4][4];
#pragma unroll
  for (int i = 0; i < 2; i++)
#pragma unroll
    for (int j = 0; j < 2; j++)
#pragma unroll
      for (int v = 0; v < 4; v++)
#pragma unroll
        for (int u = 0; u < 4; u++) acc[i][j][v][u] = 0.f;

  const int lr = tid >> 5;        // 0..7
  const int lc = (tid & 31) * 4;  // 0..124

  for (int k0 = 0; k0 < D_; k0 += 16) {
#pragma unroll
    for (int h = 0; h < 2; h++) {
      const int kk = lr + h * 8;
      float4 av = *(const float4*)(Ab + (size_t)(k0 + kk) * Q_ + q0 + lc);
      float4 bv = *(const float4*)(Bb + (size_t)(k0 + kk) * L_ + l0 + lc);
      *(float4*)&As[kk][lc] = av;
      *(float4*)&Bs[kk][lc] = bv;
    }
    __syncthreads();
#pragma unroll
    for (int k = 0; k < 16; k++) {
      float4 a0 = *(const float4*)&As[k][ty * 4];
      float4 a1 = *(const float4*)&As[k][64 + ty * 4];
      float4 b0 = *(const float4*)&Bs[k][tx * 4];
      float4 b1 = *(const float4*)&Bs[k][64 + tx * 4];
      float ar[2][4] = {{a0.x, a0.y, a0.z, a0.w}, {a1.x, a1.y, a1.z, a1.w}};
      float br[2][4] = {{b0.x, b0.y, b0.z, b0.w}, {b1.x, b1.y, b1.z, b1.w}};
#pragma unroll
      for (int i = 0; i < 2; i++)
#pragma unroll
        for (int v = 0; v < 4; v++)
#pragma unroll
          for (int j = 0; j < 2; j++)
#pragma unroll
            for (int u = 0; u < 4; u++)
              acc[i][j][v][u] += ar[i][v] * br[j][u];
    }
    __syncthreads();
  }

  float* Sb = S + (size_t)b * Q_ * L_;
#pragma unroll
  for (int i = 0; i < 2; i++)
#pragma unroll
    for (int v = 0; v < 4; v++) {
      const int q = q0 + i * 64 + ty * 4 + v;
#pragma unroll
      for (int j = 0; j < 2; j++) {
        float4 o = make_float4(acc[i][j][v][0], acc[i][j][v][1],
                               acc[i][j][v][2], acc[i][j][v][3]);
        *(float4*)(Sb + (size_t)q * L_ + l0 + j * 64 + tx * 4) = o;
      }
    }
}

// ---------------------------------------------------------------------------
// K2: per-(b,l) online softmax stats over q (first softmax, axis=q).
// Reads S once (coalesced: 64 lanes cover 256B contiguous per q-step).
// grid (L/256, B), block 256; one thread per l.
// ---------------------------------------------------------------------------
__global__ __launch_bounds__(256) void k2_stats(
    const float* __restrict__ S, float* __restrict__ maxs,
    float* __restrict__ sums) {
  const int b = blockIdx.y;
  const int l = blockIdx.x * 256 + threadIdx.x;
  const float* p = S + (size_t)b * Q_ * L_ + l;
  float m = -1e30f, s = 0.f;
#pragma unroll 8
  for (int q = 0; q < Q_; q++) {
    float x = p[(size_t)q * L_];
    float nm = fmaxf(m, x);
    s = s * __expf(m - nm) + __expf(x - nm);
    m = nm;
  }
  maxs[b * L_ + l] = m;
  sums[b * L_ + l] = s;
}

// ---------------------------------------------------------------------------
// K3: per-(b,q) row: a = exp(S - mx)/sum (first softmax value), then second
// softmax over l of 4*a. 4a in [0,4] so no max-subtraction needed (exact same
// math as the reference's max-subtracted softmax). In-place S -> attn_c.
// grid (Q, B), block 256; thread t handles l = 4t..4t+3.
// ---------------------------------------------------------------------------
__global__ __launch_bounds__(256) void k3_softmax2(
    float* __restrict__ S, const float* __restrict__ maxs,
    const float* __restrict__ sums) {
  const int q = blockIdx.x;
  const int b = blockIdx.y;
  const int t = threadIdx.x;
  const int l = t * 4;
  float* row = S + ((size_t)b * Q_ + q) * L_;
  float4 sv = *(const float4*)(row + l);
  float4 mx = *(const float4*)(maxs + b * L_ + l);
  float4 sm = *(const float4*)(sums + b * L_ + l);
  float t0 = __expf(4.f * (__expf(sv.x - mx.x) / sm.x));
  float t1 = __expf(4.f * (__expf(sv.y - mx.y) / sm.y));
  float t2 = __expf(4.f * (__expf(sv.z - mx.z) / sm.z));
  float t3 = __expf(4.f * (__expf(sv.w - mx.w) / sm.w));
  float tot = t0 + t1 + t2 + t3;
#pragma unroll
  for (int off = 32; off > 0; off >>= 1) tot += __shfl_xor(tot, off);
  __shared__ float red[4];
  if ((t & 63) == 0) red[t >> 6] = tot;
  __syncthreads();
  const float inv = 1.f / (red[0] + red[1] + red[2] + red[3]);
  float4 o = make_float4(t0 * inv, t1 * inv, t2 * inv, t3 * inv);
  *(float4*)(row + l) = o;
}

// ---------------------------------------------------------------------------
// K4: W[b][d][q] = sum_l ctx[b][d][l] * attn_c[b][q][l]
// NT GEMM: K=l is the fast dim of both -> transpose-on-LDS-store staging.
// Tile 128(d) x 64(q) x 16(l), 256 threads, 8x4 per thread.
// Pads (132 / 68 word strides) keep both scalar transpose-writes and float4
// compute-reads at <=2-way bank aliasing (free on CDNA4).
// grid (Q/64, B)
// ---------------------------------------------------------------------------
__global__ __launch_bounds__(256) void k4_weighted(
    const float* __restrict__ ctx, const float* __restrict__ Ac,
    float* __restrict__ W) {
  __shared__ float Cs[16][132];  // [l][d]
  __shared__ float As2[16][68];  // [l][q]
  const int b  = blockIdx.y;
  const int q0 = blockIdx.x * 64;
  const int tid = threadIdx.x;
  const int tx = tid & 15, ty = tid >> 4;

  const float* Cb = ctx + (size_t)b * D_ * L_;
  const float* Ab = Ac  + (size_t)b * Q_ * L_;

  float acc[2][4][4];
#pragma unroll
  for (int i = 0; i < 2; i++)
#pragma unroll
    for (int v = 0; v < 4; v++)
#pragma unroll
      for (int u = 0; u < 4; u++) acc[i][v][u] = 0.f;

  const int dr  = tid >> 2;        // 0..63
  const int lc4 = (tid & 3) * 4;   // 0,4,8,12

  for (int l0 = 0; l0 < L_; l0 += 16) {
#pragma unroll
    for (int h = 0; h < 2; h++) {
      const int d = dr + h * 64;
      float4 cv = *(const float4*)(Cb + (size_t)d * L_ + l0 + lc4);
      Cs[lc4 + 0][d] = cv.x;
      Cs[lc4 + 1][d] = cv.y;
      Cs[lc4 + 2][d] = cv.z;
      Cs[lc4 + 3][d] = cv.w;
    }
    {
      float4 av = *(const float4*)(Ab + (size_t)(q0 + dr) * L_ + l0 + lc4);
      As2[lc4 + 0][dr] = av.x;
      As2[lc4 + 1][dr] = av.y;
      As2[lc4 + 2][dr] = av.z;
      As2[lc4 + 3][dr] = av.w;
    }
    __syncthreads();
#pragma unroll
    for (int k = 0; k < 16; k++) {
      float4 a0 = *(const float4*)&Cs[k][ty * 4];
      float4 a1 = *(const float4*)&Cs[k][64 + ty * 4];
      float4 bq = *(const float4*)&As2[k][tx * 4];
      float ar[2][4] = {{a0.x, a0.y, a0.z, a0.w}, {a1.x, a1.y, a1.z, a1.w}};
      float br[4] = {bq.x, bq.y, bq.z, bq.w};
#pragma unroll
      for (int i = 0; i < 2; i++)
#pragma unroll
        for (int v = 0; v < 4; v++)
#pragma unroll
          for (int u = 0; u < 4; u++)
            acc[i][v][u] += ar[i][v] * br[u];
    }
    __syncthreads();
  }

  float* Wb = W + (size_t)b * D_ * Q_;
#pragma unroll
  for (int i = 0; i < 2; i++)
#pragma unroll
    for (int v = 0; v < 4; v++) {
      const int d = i * 64 + ty * 4 + v;
      float4 o = make_float4(acc[i][v][0], acc[i][v][1],
                             acc[i][v][2], acc[i][v][3]);
      *(float4*)(Wb + (size_t)d * Q_ + q0 + tx * 4) = o;
    }
}

// ---------------------------------------------------------------------------
// Orchestration. d_out layout: [weighted_context (B*D*Q) | attention_map
// (B*Q*L)]. The map region doubles as scratch for S (scores^T) since the
// second softmax output attn_c lands there in exactly (B,Q,L) layout.
// Softmax-1 stats live temporarily at the start of the weighted region
// (consumed by K3 before K4 overwrites it). No d_ws needed.
// ---------------------------------------------------------------------------
extern "C" void kernel_launch(void* const* d_in, const int* in_sizes, int n_in,
                              void* d_out, int out_size, void* d_ws,
                              size_t ws_size, hipStream_t stream) {
  const float* query = (const float*)d_in[0];
  const float* ctx   = (const float*)d_in[1];
  float* W    = (float*)d_out;                       // B*D*Q
  float* S    = (float*)d_out + (size_t)B_ * D_ * Q_;  // B*Q*L
  float* maxs = W;                                   // B*L floats
  float* sums = W + (size_t)B_ * L_;                 // B*L floats

  k1_scores<<<dim3(L_ / 128, Q_ / 128, B_), 256, 0, stream>>>(query, ctx, S);
  k2_stats<<<dim3(L_ / 256, B_), 256, 0, stream>>>(S, maxs, sums);
  k3_softmax2<<<dim3(Q_, B_), 256, 0, stream>>>(S, maxs, sums);
  k4_weighted<<<dim3(Q_ / 64, B_), 256, 0, stream>>>(ctx, S, W);
}

// Round 2
// 405.931 us; speedup vs baseline: 1.0904x; 1.0904x over previous
//
#include <hip/hip_runtime.h>
#include <math.h>

#define B_ 128
#define D_ 128
#define Q_ 256
#define L_ 1024
#define BLK ((size_t)B_ * L_)

typedef __attribute__((ext_vector_type(8))) short s16x8;
typedef __attribute__((ext_vector_type(4))) float f32x4;

__device__ __forceinline__ unsigned short f2bf(float x) {
  unsigned u = __float_as_uint(x);
  u += 0x7FFF + ((u >> 16) & 1);  // round-to-nearest-even
  return (unsigned short)(u >> 16);
}
__device__ __forceinline__ float bf2f(unsigned short h) {
  return __uint_as_float(((unsigned)h) << 16);
}

// ---------------------------------------------------------------------------
// K1: S[b][q][l] = sum_d query[b][d][q] * ctx[b][d][l]  via split-bf16 MFMA
// (x = hi + lo; keep hi*hi + hi*lo + lo*hi -> ~fp32-accurate scores).
// Block tile 128q x 128l, K=D=128 in BK=32 chunks. 4 waves, wave tile 64x64.
// Fragment layouts (guide-verified): A/B [m|n]=lane&15, k=quad*8+j;
// C/D row=quad*4+r, col=lane&15. LDS rows padded to 40 shorts (80B): frag
// reads 16B-aligned, 2-way bank aliasing only (free).
// Epilogue: per-l partial softmax-1 stats (max,sum over this block's 128 q)
// from accumulators -> pm/ps[qt][b][l]. grid (L/128, Q/128, B)
// ---------------------------------------------------------------------------
__global__ __launch_bounds__(256) void k1_scores(
    const float* __restrict__ query, const float* __restrict__ ctx,
    float* __restrict__ S, float* __restrict__ pm, float* __restrict__ ps) {
  __shared__ unsigned short Ah[128][40], Al[128][40];
  __shared__ unsigned short Bh[128][40], Bl[128][40];
  __shared__ float sm[2][128], ss[2][128];

  const int b = blockIdx.z, qt = blockIdx.y;
  const int q0 = qt * 128, l0 = blockIdx.x * 128;
  const int tid = threadIdx.x;
  const int w = tid >> 6, lane = tid & 63, quad = lane >> 4, l15 = lane & 15;
  const int wq = w >> 1, wl = w & 1;

  const float* Qb = query + (size_t)b * D_ * Q_;
  const float* Cb = ctx + (size_t)b * D_ * L_;

  f32x4 acc[4][4];
#pragma unroll
  for (int mi = 0; mi < 4; mi++)
#pragma unroll
    for (int ni = 0; ni < 4; ni++) acc[mi][ni] = (f32x4){0.f, 0.f, 0.f, 0.f};

  const int cc = (tid & 31) * 4;  // column within tile (q or l)
  const int kr = tid >> 5;        // 0..7

  for (int k0 = 0; k0 < D_; k0 += 32) {
    if (k0) __syncthreads();
#pragma unroll
    for (int h = 0; h < 4; h++) {
      const int k = kr + h * 8;
      float4 av = *(const float4*)(Qb + (size_t)(k0 + k) * Q_ + q0 + cc);
      float4 bv = *(const float4*)(Cb + (size_t)(k0 + k) * L_ + l0 + cc);
      float aa[4] = {av.x, av.y, av.z, av.w};
      float bb[4] = {bv.x, bv.y, bv.z, bv.w};
#pragma unroll
      for (int j = 0; j < 4; j++) {
        unsigned short h1 = f2bf(aa[j]);
        Ah[cc + j][k] = h1;
        Al[cc + j][k] = f2bf(aa[j] - bf2f(h1));
        unsigned short h2 = f2bf(bb[j]);
        Bh[cc + j][k] = h2;
        Bl[cc + j][k] = f2bf(bb[j] - bf2f(h2));
      }
    }
    __syncthreads();

    s16x8 ah[4], al[4], bh[4], bl[4];
#pragma unroll
    for (int mi = 0; mi < 4; mi++) {
      ah[mi] = *(const s16x8*)&Ah[wq * 64 + mi * 16 + l15][quad * 8];
      al[mi] = *(const s16x8*)&Al[wq * 64 + mi * 16 + l15][quad * 8];
    }
#pragma unroll
    for (int ni = 0; ni < 4; ni++) {
      bh[ni] = *(const s16x8*)&Bh[wl * 64 + ni * 16 + l15][quad * 8];
      bl[ni] = *(const s16x8*)&Bl[wl * 64 + ni * 16 + l15][quad * 8];
    }
#pragma unroll
    for (int mi = 0; mi < 4; mi++)
#pragma unroll
      for (int ni = 0; ni < 4; ni++) {
        acc[mi][ni] = __builtin_amdgcn_mfma_f32_16x16x32_bf16(
            ah[mi], bh[ni], acc[mi][ni], 0, 0, 0);
        acc[mi][ni] = __builtin_amdgcn_mfma_f32_16x16x32_bf16(
            ah[mi], bl[ni], acc[mi][ni], 0, 0, 0);
        acc[mi][ni] = __builtin_amdgcn_mfma_f32_16x16x32_bf16(
            al[mi], bh[ni], acc[mi][ni], 0, 0, 0);
      }
  }

  // store S (fp32): row q = q0 + wq*64 + mi*16 + quad*4 + r, col l = l0 + ...
  float* Sb = S + ((size_t)b * Q_ + q0) * L_ + l0;
#pragma unroll
  for (int mi = 0; mi < 4; mi++)
#pragma unroll
    for (int ni = 0; ni < 4; ni++)
#pragma unroll
      for (int r = 0; r < 4; r++)
        Sb[(size_t)(wq * 64 + mi * 16 + quad * 4 + r) * L_ + wl * 64 +
           ni * 16 + l15] = acc[mi][ni][r];

  // softmax-1 partial stats over this block's 128 q, per l column
#pragma unroll
  for (int ni = 0; ni < 4; ni++) {
    float m = -1e30f;
#pragma unroll
    for (int mi = 0; mi < 4; mi++)
#pragma unroll
      for (int r = 0; r < 4; r++) m = fmaxf(m, acc[mi][ni][r]);
    m = fmaxf(m, __shfl_xor(m, 16));
    m = fmaxf(m, __shfl_xor(m, 32));
    float s = 0.f;
#pragma unroll
    for (int mi = 0; mi < 4; mi++)
#pragma unroll
      for (int r = 0; r < 4; r++) s += __expf(acc[mi][ni][r] - m);
    s += __shfl_xor(s, 16);
    s += __shfl_xor(s, 32);
    if (quad == 0) {
      sm[wq][wl * 64 + ni * 16 + l15] = m;
      ss[wq][wl * 64 + ni * 16 + l15] = s;
    }
  }
  __syncthreads();
  if (tid < 128) {
    float m0 = sm[0][tid], m1 = sm[1][tid];
    float M = fmaxf(m0, m1);
    float Sv = ss[0][tid] * __expf(m0 - M) + ss[1][tid] * __expf(m1 - M);
    pm[(size_t)qt * BLK + (size_t)b * L_ + l0 + tid] = M;
    ps[(size_t)qt * BLK + (size_t)b * L_ + l0 + tid] = Sv;
  }
}

// ---------------------------------------------------------------------------
// K2: combine the 2 q-tile partials into final per-(b,l) softmax-1 stats.
// grid (B*L/256). ~2 MB traffic.
// ---------------------------------------------------------------------------
__global__ __launch_bounds__(256) void k2_combine(
    const float* __restrict__ pm, const float* __restrict__ ps,
    float* __restrict__ fm, float* __restrict__ fs) {
  const size_t i = (size_t)blockIdx.x * 256 + threadIdx.x;
  float m0 = pm[i], m1 = pm[BLK + i];
  float M = fmaxf(m0, m1);
  float s = ps[i] * __expf(m0 - M) + ps[BLK + i] * __expf(m1 - M);
  fm[i] = M;
  fs[i] = s;
}

// ---------------------------------------------------------------------------
// K3: per-(b,q) row: a = exp(S - mx)/sum, then softmax over l of 4a
// (4a in [0,4] -> no max-subtract needed). In-place S -> attn_c (fp32 map).
// grid (Q, B), block 256.
// ---------------------------------------------------------------------------
__global__ __launch_bounds__(256) void k3_softmax2(
    float* __restrict__ S, const float* __restrict__ fm,
    const float* __restrict__ fs) {
  const int q = blockIdx.x;
  const int b = blockIdx.y;
  const int t = threadIdx.x;
  const int l = t * 4;
  float* row = S + ((size_t)b * Q_ + q) * L_;
  float4 sv = *(const float4*)(row + l);
  float4 mx = *(const float4*)(fm + (size_t)b * L_ + l);
  float4 smv = *(const float4*)(fs + (size_t)b * L_ + l);
  float t0 = __expf(4.f * (__expf(sv.x - mx.x) / smv.x));
  float t1 = __expf(4.f * (__expf(sv.y - mx.y) / smv.y));
  float t2 = __expf(4.f * (__expf(sv.z - mx.z) / smv.z));
  float t3 = __expf(4.f * (__expf(sv.w - mx.w) / smv.w));
  float tot = t0 + t1 + t2 + t3;
#pragma unroll
  for (int off = 32; off > 0; off >>= 1) tot += __shfl_xor(tot, off);
  __shared__ float red[4];
  if ((t & 63) == 0) red[t >> 6] = tot;
  __syncthreads();
  const float inv = 1.f / (red[0] + red[1] + red[2] + red[3]);
  float4 o = make_float4(t0 * inv, t1 * inv, t2 * inv, t3 * inv);
  *(float4*)(row + l) = o;
}

// ---------------------------------------------------------------------------
// K4: W[b][d][q] = sum_l ctx[b][d][l] * attn_c[b][q][l]  via bf16 MFMA.
// A = ctx [d][l] (already k-fastest), B = attn_c [q][l] (k-fastest): no
// transposes. Block tile 128d x 64q, K=L=1024, BK=64; 4 waves 2x2, wave
// tile 64d x 32q. Staging: float4 load -> packed bf16 uint2 LDS write.
// Rows padded to 72 shorts (144B): frag reads 16B-aligned, 2-way only.
// grid (Q/64, B)
// ---------------------------------------------------------------------------
__global__ __launch_bounds__(256) void k4_weighted(
    const float* __restrict__ ctx, const float* __restrict__ attn,
    float* __restrict__ W) {
  __shared__ unsigned short As[128][72];
  __shared__ unsigned short Bs[64][72];
  const int b = blockIdx.y, q0 = blockIdx.x * 64;
  const int tid = threadIdx.x;
  const int w = tid >> 6, lane = tid & 63, quad = lane >> 4, l15 = lane & 15;
  const int wd = (w >> 1) * 64, wn = (w & 1) * 32;

  const float* Cb = ctx + (size_t)b * D_ * L_;
  const float* Ab = attn + ((size_t)b * Q_ + q0) * L_;

  f32x4 acc[4][2];
#pragma unroll
  for (int mi = 0; mi < 4; mi++)
#pragma unroll
    for (int ni = 0; ni < 2; ni++) acc[mi][ni] = (f32x4){0.f, 0.f, 0.f, 0.f};

  const int a_lr = (tid & 15) * 4, a_dr = tid >> 4;  // A: 16 cols x 16 rows
  const int b_qr = tid >> 2, b_lb = (tid & 3) * 4;   // B: 4 cols x 64 rows

  for (int l0 = 0; l0 < L_; l0 += 64) {
    if (l0) __syncthreads();
#pragma unroll
    for (int h = 0; h < 8; h++) {  // A: 128d x 64l
      const int d = a_dr + h * 16;
      float4 cv = *(const float4*)(Cb + (size_t)d * L_ + l0 + a_lr);
      uint2 pk;
      pk.x = (unsigned)f2bf(cv.x) | ((unsigned)f2bf(cv.y) << 16);
      pk.y = (unsigned)f2bf(cv.z) | ((unsigned)f2bf(cv.w) << 16);
      *(uint2*)&As[d][a_lr] = pk;
    }
#pragma unroll
    for (int h = 0; h < 4; h++) {  // B: 64q x 64l
      const int l = b_lb + h * 16;
      float4 av = *(const float4*)(Ab + (size_t)b_qr * L_ + l0 + l);
      uint2 pk;
      pk.x = (unsigned)f2bf(av.x) | ((unsigned)f2bf(av.y) << 16);
      pk.y = (unsigned)f2bf(av.z) | ((unsigned)f2bf(av.w) << 16);
      *(uint2*)&Bs[b_qr][l] = pk;
    }
    __syncthreads();

#pragma unroll
    for (int ks = 0; ks < 2; ks++) {
      s16x8 af[4], bf[2];
#pragma unroll
      for (int mi = 0; mi < 4; mi++)
        af[mi] = *(const s16x8*)&As[wd + mi * 16 + l15][ks * 32 + quad * 8];
#pragma unroll
      for (int ni = 0; ni < 2; ni++)
        bf[ni] = *(const s16x8*)&Bs[wn + ni * 16 + l15][ks * 32 + quad * 8];
#pragma unroll
      for (int mi = 0; mi < 4; mi++)
#pragma unroll
        for (int ni = 0; ni < 2; ni++)
          acc[mi][ni] = __builtin_amdgcn_mfma_f32_16x16x32_bf16(
              af[mi], bf[ni], acc[mi][ni], 0, 0, 0);
    }
  }

  float* Wb = W + (size_t)b * D_ * Q_;
#pragma unroll
  for (int mi = 0; mi < 4; mi++)
#pragma unroll
    for (int ni = 0; ni < 2; ni++)
#pragma unroll
      for (int r = 0; r < 4; r++)
        Wb[(size_t)(wd + mi * 16 + quad * 4 + r) * Q_ + q0 + wn + ni * 16 +
           l15] = acc[mi][ni][r];
}

// ---------------------------------------------------------------------------
// d_out layout: [W (B*D*Q) | attention_map (B*Q*L)]. Map region doubles as S
// scratch (attn_c lands there in (B,Q,L) = final layout). Softmax-1 stats
// (partials + finals, 3 MB) live at the head of the W region, consumed by K3
// before K4 overwrites W. No d_ws needed.
// ---------------------------------------------------------------------------
extern "C" void kernel_launch(void* const* d_in, const int* in_sizes, int n_in,
                              void* d_out, int out_size, void* d_ws,
                              size_t ws_size, hipStream_t stream) {
  const float* query = (const float*)d_in[0];
  const float* ctx = (const float*)d_in[1];
  float* W = (float*)d_out;
  float* S = (float*)d_out + (size_t)B_ * D_ * Q_;
  float* pm = W;            // [2][B*L]
  float* ps = W + 2 * BLK;  // [2][B*L]
  float* fm = W + 4 * BLK;  // [B*L]
  float* fs = W + 5 * BLK;  // [B*L]  (6*BL = 3 MB << B*D*Q region)

  k1_scores<<<dim3(L_ / 128, Q_ / 128, B_), 256, 0, stream>>>(query, ctx, S,
                                                              pm, ps);
  k2_combine<<<dim3((unsigned)(BLK / 256)), 256, 0, stream>>>(pm, ps, fm, fs);
  k3_softmax2<<<dim3(Q_, B_), 256, 0, stream>>>(S, fm, fs);
  k4_weighted<<<dim3(Q_ / 64, B_), 256, 0, stream>>>(ctx, S, W);
}

// Round 3
// 331.890 us; speedup vs baseline: 1.3336x; 1.2231x over previous
//
#include <hip/hip_runtime.h>
#include <math.h>

#define B_ 128
#define D_ 128
#define Q_ 256
#define L_ 1024
#define BLK ((size_t)B_ * L_)

typedef __attribute__((ext_vector_type(8))) short s16x8;
typedef __attribute__((ext_vector_type(4))) float f32x4;

__device__ __forceinline__ unsigned short f2bf(float x) {
  unsigned u = __float_as_uint(x);
  u += 0x7FFF + ((u >> 16) & 1);  // round-to-nearest-even
  return (unsigned short)(u >> 16);
}
__device__ __forceinline__ float bf2f(unsigned short h) {
  return __uint_as_float(((unsigned)h) << 16);
}
__device__ __forceinline__ uint2 pack4bf(float4 v) {
  uint2 r;
  r.x = ((unsigned)f2bf(v.y) << 16) | (unsigned)f2bf(v.x);
  r.y = ((unsigned)f2bf(v.w) << 16) | (unsigned)f2bf(v.z);
  return r;
}

// ---------------------------------------------------------------------------
// K1: S[b][q][l] = sum_d query[b][d][q] * ctx[b][d][l], split-bf16 MFMA
// (hi*hi + hi*lo + lo*hi). Staging: fp32 tiles in NATURAL [k][col] layout
// (float4 writes, <=4-way), transpose happens on the READ side: scalar
// ds_read_b32 column reads with 129-word (odd) row stride -> per-instr banks
// 8*quad + l15 = exactly 2 lanes/bank (free). hi/lo split in registers.
// Block 128q x 128l, BK=32, 4 waves (wave tile 64x64, 4x4 frags).
// Epilogue: S store + per-l partial softmax-1 stats. grid (L/128, Q/128, B)
// ---------------------------------------------------------------------------
__global__ __launch_bounds__(256) void k1_scores(
    const float* __restrict__ query, const float* __restrict__ ctx,
    float* __restrict__ S, float* __restrict__ pm, float* __restrict__ ps) {
  __shared__ float Af[32][129];  // [k][q]
  __shared__ float Bf[32][129];  // [k][l]
  __shared__ float sm[2][128], ss[2][128];

  const int b = blockIdx.z, qt = blockIdx.y;
  const int q0 = qt * 128, l0 = blockIdx.x * 128;
  const int tid = threadIdx.x;
  const int w = tid >> 6, lane = tid & 63, quad = lane >> 4, l15 = lane & 15;
  const int wq = w >> 1, wl = w & 1;

  const float* Qb = query + (size_t)b * D_ * Q_;
  const float* Cb = ctx + (size_t)b * D_ * L_;

  f32x4 acc[4][4];
#pragma unroll
  for (int mi = 0; mi < 4; mi++)
#pragma unroll
    for (int ni = 0; ni < 4; ni++) acc[mi][ni] = (f32x4){0.f, 0.f, 0.f, 0.f};

  const int cc = (tid & 31) * 4;  // column within tile
  const int kr = tid >> 5;        // 0..7

  for (int k0 = 0; k0 < D_; k0 += 32) {
    if (k0) __syncthreads();
#pragma unroll
    for (int h = 0; h < 4; h++) {
      const int k = kr + h * 8;
      *(float4*)&Af[k][cc] =
          *(const float4*)(Qb + (size_t)(k0 + k) * Q_ + q0 + cc);
      *(float4*)&Bf[k][cc] =
          *(const float4*)(Cb + (size_t)(k0 + k) * L_ + l0 + cc);
    }
    __syncthreads();

    s16x8 ah[4], al[4], bh[4], bl[4];
#pragma unroll
    for (int mi = 0; mi < 4; mi++) {
      const int row = wq * 64 + mi * 16 + l15;
#pragma unroll
      for (int j = 0; j < 8; j++) {
        float x = Af[quad * 8 + j][row];
        unsigned short h1 = f2bf(x);
        ah[mi][j] = (short)h1;
        al[mi][j] = (short)f2bf(x - bf2f(h1));
      }
    }
#pragma unroll
    for (int ni = 0; ni < 4; ni++) {
      const int row = wl * 64 + ni * 16 + l15;
#pragma unroll
      for (int j = 0; j < 8; j++) {
        float x = Bf[quad * 8 + j][row];
        unsigned short h1 = f2bf(x);
        bh[ni][j] = (short)h1;
        bl[ni][j] = (short)f2bf(x - bf2f(h1));
      }
    }
#pragma unroll
    for (int mi = 0; mi < 4; mi++)
#pragma unroll
      for (int ni = 0; ni < 4; ni++) {
        acc[mi][ni] = __builtin_amdgcn_mfma_f32_16x16x32_bf16(
            ah[mi], bh[ni], acc[mi][ni], 0, 0, 0);
        acc[mi][ni] = __builtin_amdgcn_mfma_f32_16x16x32_bf16(
            ah[mi], bl[ni], acc[mi][ni], 0, 0, 0);
        acc[mi][ni] = __builtin_amdgcn_mfma_f32_16x16x32_bf16(
            al[mi], bh[ni], acc[mi][ni], 0, 0, 0);
      }
  }

  // S store: row q = q0 + wq*64 + mi*16 + quad*4 + r, col l = l0 + ...
  float* Sb = S + ((size_t)b * Q_ + q0) * L_ + l0;
#pragma unroll
  for (int mi = 0; mi < 4; mi++)
#pragma unroll
    for (int ni = 0; ni < 4; ni++)
#pragma unroll
      for (int r = 0; r < 4; r++)
        Sb[(size_t)(wq * 64 + mi * 16 + quad * 4 + r) * L_ + wl * 64 +
           ni * 16 + l15] = acc[mi][ni][r];

  // softmax-1 partial stats over this block's 128 q, per l column
#pragma unroll
  for (int ni = 0; ni < 4; ni++) {
    float m = -1e30f;
#pragma unroll
    for (int mi = 0; mi < 4; mi++)
#pragma unroll
      for (int r = 0; r < 4; r++) m = fmaxf(m, acc[mi][ni][r]);
    m = fmaxf(m, __shfl_xor(m, 16));
    m = fmaxf(m, __shfl_xor(m, 32));
    float s = 0.f;
#pragma unroll
    for (int mi = 0; mi < 4; mi++)
#pragma unroll
      for (int r = 0; r < 4; r++) s += __expf(acc[mi][ni][r] - m);
    s += __shfl_xor(s, 16);
    s += __shfl_xor(s, 32);
    if (quad == 0) {
      sm[wq][wl * 64 + ni * 16 + l15] = m;
      ss[wq][wl * 64 + ni * 16 + l15] = s;
    }
  }
  __syncthreads();
  if (tid < 128) {
    float m0 = sm[0][tid], m1 = sm[1][tid];
    float M = fmaxf(m0, m1);
    float Sv = ss[0][tid] * __expf(m0 - M) + ss[1][tid] * __expf(m1 - M);
    pm[(size_t)qt * BLK + (size_t)b * L_ + l0 + tid] = M;
    ps[(size_t)qt * BLK + (size_t)b * L_ + l0 + tid] = Sv;
  }
}

// ---------------------------------------------------------------------------
// K2: combine the 2 q-tile partials into final per-(b,l) softmax-1 stats.
// ---------------------------------------------------------------------------
__global__ __launch_bounds__(256) void k2_combine(
    const float* __restrict__ pm, const float* __restrict__ ps,
    float* __restrict__ fm, float* __restrict__ fs) {
  const size_t i = (size_t)blockIdx.x * 256 + threadIdx.x;
  float m0 = pm[i], m1 = pm[BLK + i];
  float M = fmaxf(m0, m1);
  float s = ps[i] * __expf(m0 - M) + ps[BLK + i] * __expf(m1 - M);
  fm[i] = M;
  fs[i] = s;
}

// ---------------------------------------------------------------------------
// K3: per-(b,q) row: a = exp(S - mx)/sum, then softmax over l of 4a
// (4a in [0,4] -> no max-subtract needed). In-place S -> attn_c (fp32 map).
// grid (Q, B), block 256.
// ---------------------------------------------------------------------------
__global__ __launch_bounds__(256) void k3_softmax2(
    float* __restrict__ S, const float* __restrict__ fm,
    const float* __restrict__ fs) {
  const int q = blockIdx.x;
  const int b = blockIdx.y;
  const int t = threadIdx.x;
  const int l = t * 4;
  float* row = S + ((size_t)b * Q_ + q) * L_;
  float4 sv = *(const float4*)(row + l);
  float4 mx = *(const float4*)(fm + (size_t)b * L_ + l);
  float4 smv = *(const float4*)(fs + (size_t)b * L_ + l);
  float t0 = __expf(4.f * (__expf(sv.x - mx.x) / smv.x));
  float t1 = __expf(4.f * (__expf(sv.y - mx.y) / smv.y));
  float t2 = __expf(4.f * (__expf(sv.z - mx.z) / smv.z));
  float t3 = __expf(4.f * (__expf(sv.w - mx.w) / smv.w));
  float tot = t0 + t1 + t2 + t3;
#pragma unroll
  for (int off = 32; off > 0; off >>= 1) tot += __shfl_xor(tot, off);
  __shared__ float red[4];
  if ((t & 63) == 0) red[t >> 6] = tot;
  __syncthreads();
  const float inv = 1.f / (red[0] + red[1] + red[2] + red[3]);
  float4 o = make_float4(t0 * inv, t1 * inv, t2 * inv, t3 * inv);
  *(float4*)(row + l) = o;
}

// ---------------------------------------------------------------------------
// K4: W[b][d][q] = sum_l ctx[b][d][l] * attn_c[b][q][l], plain bf16 MFMA.
// m97-proven LDS pattern: BK=32, unpadded [row][32]-short layout; frag-read
// start banks cover all 8 16B groups. Staging: float4 fp32 load -> packed
// bf16 uint2 write. Block 128d x 64q, 4 waves (wave tile 64d x 32q).
// grid (Q/64, B)
// ---------------------------------------------------------------------------
__global__ __launch_bounds__(256) void k4_weighted(
    const float* __restrict__ ctx, const float* __restrict__ attn,
    float* __restrict__ W) {
  __shared__ unsigned short As[128][32];  // [d][l]
  __shared__ unsigned short Bs[64][32];   // [q][l]
  const int b = blockIdx.y, q0 = blockIdx.x * 64;
  const int tid = threadIdx.x;
  const int w = tid >> 6, lane = tid & 63, quad = lane >> 4, l15 = lane & 15;
  const int wd = (w >> 1) * 64, wn = (w & 1) * 32;

  const float* Cb = ctx + (size_t)b * D_ * L_;
  const float* Ab = attn + ((size_t)b * Q_ + q0) * L_;

  f32x4 acc[4][2];
#pragma unroll
  for (int mi = 0; mi < 4; mi++)
#pragma unroll
    for (int ni = 0; ni < 2; ni++) acc[mi][ni] = (f32x4){0.f, 0.f, 0.f, 0.f};

  const int lc = (tid & 7) * 4;  // 0..28
  const int rr = tid >> 3;       // 0..31

  for (int l0 = 0; l0 < L_; l0 += 32) {
    if (l0) __syncthreads();
#pragma unroll
    for (int h = 0; h < 4; h++) {  // A: 128d x 32l
      const int d = rr + h * 32;
      float4 cv = *(const float4*)(Cb + (size_t)d * L_ + l0 + lc);
      *(uint2*)&As[d][lc] = pack4bf(cv);
    }
#pragma unroll
    for (int h = 0; h < 2; h++) {  // B: 64q x 32l
      const int q = rr + h * 32;
      float4 av = *(const float4*)(Ab + (size_t)q * L_ + l0 + lc);
      *(uint2*)&Bs[q][lc] = pack4bf(av);
    }
    __syncthreads();

    s16x8 af[4], bq[2];
#pragma unroll
    for (int mi = 0; mi < 4; mi++)
      af[mi] = *(const s16x8*)&As[wd + mi * 16 + l15][quad * 8];
#pragma unroll
    for (int ni = 0; ni < 2; ni++)
      bq[ni] = *(const s16x8*)&Bs[wn + ni * 16 + l15][quad * 8];
#pragma unroll
    for (int mi = 0; mi < 4; mi++)
#pragma unroll
      for (int ni = 0; ni < 2; ni++)
        acc[mi][ni] = __builtin_amdgcn_mfma_f32_16x16x32_bf16(
            af[mi], bq[ni], acc[mi][ni], 0, 0, 0);
  }

  float* Wb = W + (size_t)b * D_ * Q_;
#pragma unroll
  for (int mi = 0; mi < 4; mi++)
#pragma unroll
    for (int ni = 0; ni < 2; ni++)
#pragma unroll
      for (int r = 0; r < 4; r++)
        Wb[(size_t)(wd + mi * 16 + quad * 4 + r) * Q_ + q0 + wn + ni * 16 +
           l15] = acc[mi][ni][r];
}

// ---------------------------------------------------------------------------
// d_out layout: [W (B*D*Q) | attention_map (B*Q*L)]. Map region doubles as S
// scratch (attn_c lands there in (B,Q,L) = final layout). Softmax-1 stats
// (3 MB) live at the head of the W region, consumed by K3 before K4
// overwrites W. No d_ws needed.
// ---------------------------------------------------------------------------
extern "C" void kernel_launch(void* const* d_in, const int* in_sizes, int n_in,
                              void* d_out, int out_size, void* d_ws,
                              size_t ws_size, hipStream_t stream) {
  const float* query = (const float*)d_in[0];
  const float* ctx = (const float*)d_in[1];
  float* W = (float*)d_out;
  float* S = (float*)d_out + (size_t)B_ * D_ * Q_;
  float* pm = W;            // [2][B*L]
  float* ps = W + 2 * BLK;  // [2][B*L]
  float* fm = W + 4 * BLK;  // [B*L]
  float* fs = W + 5 * BLK;  // [B*L]

  k1_scores<<<dim3(L_ / 128, Q_ / 128, B_), 256, 0, stream>>>(query, ctx, S,
                                                              pm, ps);
  k2_combine<<<dim3((unsigned)(BLK / 256)), 256, 0, stream>>>(pm, ps, fm, fs);
  k3_softmax2<<<dim3(Q_, B_), 256, 0, stream>>>(S, fm, fs);
  k4_weighted<<<dim3(Q_ / 64, B_), 256, 0, stream>>>(ctx, S, W);
}

// Round 4
// 316.846 us; speedup vs baseline: 1.3969x; 1.0475x over previous
//
#include <hip/hip_runtime.h>
#include <math.h>

#define B_ 128
#define D_ 128
#define Q_ 256
#define L_ 1024

typedef __attribute__((ext_vector_type(8))) short s16x8;
typedef __attribute__((ext_vector_type(4))) float f32x4;

__device__ __forceinline__ unsigned short f2bf(float x) {
  unsigned u = __float_as_uint(x);
  u += 0x7FFF + ((u >> 16) & 1);  // round-to-nearest-even
  return (unsigned short)(u >> 16);
}
__device__ __forceinline__ float bf2f(unsigned short h) {
  return __uint_as_float(((unsigned)h) << 16);
}
__device__ __forceinline__ uint2 pack4bf(float4 v) {
  uint2 r;
  r.x = ((unsigned)f2bf(v.y) << 16) | (unsigned)f2bf(v.x);
  r.y = ((unsigned)f2bf(v.w) << 16) | (unsigned)f2bf(v.z);
  return r;
}
__device__ __forceinline__ void split8(const float* x, s16x8& hi, s16x8& lo) {
#pragma unroll
  for (int j = 0; j < 8; j++) {
    unsigned short h = f2bf(x[j]);
    hi[j] = (short)h;
    lo[j] = (short)f2bf(x[j] - bf2f(h));
  }
}

// ---------------------------------------------------------------------------
// K1: attn_q[b][q][l] = softmax_q(S)[l][q] laid out (B,Q,L), where
// S = query^T(ctx) via split-bf16 MFMA (hh+hl+lh ~ fp32 scores).
// NO LDS GEMM: TN layout (k slow, m/n fast) lets each lane load its MFMA
// fragments straight from global — lane l15 runs along the fast dim (4x64B
// segments per instr, fully coalesced); re-reads hit L2/L3 (inputs 80MB<L3).
// Block = full Q (256q) x 64l, 4 waves (one 64q strip each), BK=32.
// Epilogue: first softmax is FINAL in-block (full Q) -> write attn_q fp32,
// plus per-(q) partial second-softmax denominators sum_l exp(4a) for this
// l-tile -> pd[lt][b][q]. grid (L/64=16, B)
// ---------------------------------------------------------------------------
__global__ __launch_bounds__(256, 2) void k1_attnq(
    const float* __restrict__ query, const float* __restrict__ ctx,
    float* __restrict__ attq, float* __restrict__ pd) {
  __shared__ float sm[4][64], ss[4][64], fm[64], fs[64];
  const int lt = blockIdx.x, b = blockIdx.y;
  const int l0 = lt * 64;
  const int tid = threadIdx.x;
  const int wq = tid >> 6;  // wave = q-strip (0..3)
  const int lane = tid & 63, quad = lane >> 4, l15 = lane & 15;

  const float* Qb = query + (size_t)b * D_ * Q_;
  const float* Cb = ctx + (size_t)b * D_ * L_ + l0;

  f32x4 acc[4][4];
#pragma unroll
  for (int mi = 0; mi < 4; mi++)
#pragma unroll
    for (int ni = 0; ni < 4; ni++) acc[mi][ni] = (f32x4){0.f, 0.f, 0.f, 0.f};

#pragma unroll 2
  for (int k0 = 0; k0 < D_; k0 += 32) {
    const int kq = k0 + quad * 8;  // this lane's 8 k rows
    s16x8 ah[4], al[4], bh[4], bl[4];
#pragma unroll
    for (int mi = 0; mi < 4; mi++) {
      const float* p = Qb + (size_t)kq * Q_ + wq * 64 + mi * 16 + l15;
      float x[8];
#pragma unroll
      for (int j = 0; j < 8; j++) x[j] = p[(size_t)j * Q_];
      split8(x, ah[mi], al[mi]);
    }
#pragma unroll
    for (int ni = 0; ni < 4; ni++) {
      const float* p = Cb + (size_t)kq * L_ + ni * 16 + l15;
      float x[8];
#pragma unroll
      for (int j = 0; j < 8; j++) x[j] = p[(size_t)j * L_];
      split8(x, bh[ni], bl[ni]);
    }
#pragma unroll
    for (int mi = 0; mi < 4; mi++)
#pragma unroll
      for (int ni = 0; ni < 4; ni++) {
        acc[mi][ni] = __builtin_amdgcn_mfma_f32_16x16x32_bf16(
            ah[mi], bh[ni], acc[mi][ni], 0, 0, 0);
        acc[mi][ni] = __builtin_amdgcn_mfma_f32_16x16x32_bf16(
            ah[mi], bl[ni], acc[mi][ni], 0, 0, 0);
        acc[mi][ni] = __builtin_amdgcn_mfma_f32_16x16x32_bf16(
            al[mi], bh[ni], acc[mi][ni], 0, 0, 0);
      }
  }

  // ---- first softmax (over q), final in-block since block covers all 256 q
  // per-wave stats over its 64 q, per l column (C/D: row=quad*4+r, col=l15)
#pragma unroll
  for (int ni = 0; ni < 4; ni++) {
    float m = -1e30f;
#pragma unroll
    for (int mi = 0; mi < 4; mi++)
#pragma unroll
      for (int r = 0; r < 4; r++) m = fmaxf(m, acc[mi][ni][r]);
    m = fmaxf(m, __shfl_xor(m, 16));
    m = fmaxf(m, __shfl_xor(m, 32));
    float s = 0.f;
#pragma unroll
    for (int mi = 0; mi < 4; mi++)
#pragma unroll
      for (int r = 0; r < 4; r++) s += __expf(acc[mi][ni][r] - m);
    s += __shfl_xor(s, 16);
    s += __shfl_xor(s, 32);
    if (quad == 0) {
      sm[wq][ni * 16 + l15] = m;
      ss[wq][ni * 16 + l15] = s;
    }
  }
  __syncthreads();
  if (tid < 64) {
    float m0 = sm[0][tid], m1 = sm[1][tid], m2 = sm[2][tid], m3 = sm[3][tid];
    float M = fmaxf(fmaxf(m0, m1), fmaxf(m2, m3));
    float S = ss[0][tid] * __expf(m0 - M) + ss[1][tid] * __expf(m1 - M) +
              ss[2][tid] * __expf(m2 - M) + ss[3][tid] * __expf(m3 - M);
    fm[tid] = M;
    fs[tid] = 1.f / S;
  }
  __syncthreads();

  float fmv[4], fiv[4];
#pragma unroll
  for (int ni = 0; ni < 4; ni++) {
    fmv[ni] = fm[ni * 16 + l15];
    fiv[ni] = fs[ni * 16 + l15];
  }
  float* Ab = attq + ((size_t)b * Q_ + wq * 64) * L_ + l0;
  float dsum[4][4];
#pragma unroll
  for (int mi = 0; mi < 4; mi++)
#pragma unroll
    for (int r = 0; r < 4; r++) dsum[mi][r] = 0.f;
#pragma unroll
  for (int mi = 0; mi < 4; mi++)
#pragma unroll
    for (int r = 0; r < 4; r++) {
      const int q = mi * 16 + quad * 4 + r;
#pragma unroll
      for (int ni = 0; ni < 4; ni++) {
        float a = __expf(acc[mi][ni][r] - fmv[ni]) * fiv[ni];
        Ab[(size_t)q * L_ + ni * 16 + l15] = a;
        dsum[mi][r] += __expf(4.f * a);
      }
    }
  // reduce dsum over the 16 l15 lanes (l columns) of each quad
#pragma unroll
  for (int mi = 0; mi < 4; mi++)
#pragma unroll
    for (int r = 0; r < 4; r++) {
      float v = dsum[mi][r];
      v += __shfl_xor(v, 1);
      v += __shfl_xor(v, 2);
      v += __shfl_xor(v, 4);
      v += __shfl_xor(v, 8);
      dsum[mi][r] = v;
    }
  if (l15 == 0) {
#pragma unroll
    for (int mi = 0; mi < 4; mi++)
#pragma unroll
      for (int r = 0; r < 4; r++)
        pd[(size_t)lt * (B_ * Q_) + b * Q_ + wq * 64 + mi * 16 + quad * 4 +
           r] = dsum[mi][r];
  }
}

// ---------------------------------------------------------------------------
// K2: invd[b][q] = 1 / sum over 16 l-tile partial denominators. 2 MB read.
// ---------------------------------------------------------------------------
__global__ __launch_bounds__(256) void k2_invd(const float* __restrict__ pd,
                                               float* __restrict__ invd) {
  const int i = blockIdx.x * 256 + threadIdx.x;  // 0..B*Q-1
  float s = 0.f;
#pragma unroll
  for (int t = 0; t < 16; t++) s += pd[(size_t)t * (B_ * Q_) + i];
  invd[i] = 1.f / s;
}

// ---------------------------------------------------------------------------
// K4: W[b][d][q] = sum_l ctx[b][d][l] * attn_c[b][q][l], bf16 MFMA,
// with the SECOND SOFTMAX fused into B-staging: read attn_q fp32, compute
// attn_c = exp(4a)*invd[q] (1 exp + 1 mul), write the attention map IN PLACE
// (each (b,q,l) staged exactly once), stage bf16 for MFMA. m97-style LDS:
// BK=32, unpadded [row][32]-short layout. Block 128d x 64q, 4 waves.
// grid (Q/64, B)
// ---------------------------------------------------------------------------
__global__ __launch_bounds__(256) void k4_weighted(
    const float* __restrict__ ctx, float* __restrict__ attn,
    const float* __restrict__ invd, float* __restrict__ W) {
  __shared__ unsigned short As[128][32];  // [d][l]
  __shared__ unsigned short Bs[64][32];   // [q][l]
  const int b = blockIdx.y, q0 = blockIdx.x * 64;
  const int tid = threadIdx.x;
  const int w = tid >> 6, lane = tid & 63, quad = lane >> 4, l15 = lane & 15;
  const int wd = (w >> 1) * 64, wn = (w & 1) * 32;

  const float* Cb = ctx + (size_t)b * D_ * L_;
  float* Ab = attn + ((size_t)b * Q_ + q0) * L_;

  const int lc = (tid & 7) * 4;  // 0..28
  const int rr = tid >> 3;       // 0..31
  const float id0 = invd[b * Q_ + q0 + rr];
  const float id1 = invd[b * Q_ + q0 + rr + 32];

  f32x4 acc[4][2];
#pragma unroll
  for (int mi = 0; mi < 4; mi++)
#pragma unroll
    for (int ni = 0; ni < 2; ni++) acc[mi][ni] = (f32x4){0.f, 0.f, 0.f, 0.f};

  for (int l0 = 0; l0 < L_; l0 += 32) {
    if (l0) __syncthreads();
#pragma unroll
    for (int h = 0; h < 4; h++) {  // A: 128d x 32l
      const int d = rr + h * 32;
      float4 cv = *(const float4*)(Cb + (size_t)d * L_ + l0 + lc);
      *(uint2*)&As[d][lc] = pack4bf(cv);
    }
#pragma unroll
    for (int h = 0; h < 2; h++) {  // B: 64q x 32l, fused second softmax
      const int q = rr + h * 32;
      float* p = Ab + (size_t)q * L_ + l0 + lc;
      float4 a = *(const float4*)p;
      const float idv = h ? id1 : id0;
      float4 t;
      t.x = __expf(4.f * a.x) * idv;
      t.y = __expf(4.f * a.y) * idv;
      t.z = __expf(4.f * a.z) * idv;
      t.w = __expf(4.f * a.w) * idv;
      *(float4*)p = t;  // attention map, in place
      *(uint2*)&Bs[q][lc] = pack4bf(t);
    }
    __syncthreads();

    s16x8 af[4], bq[2];
#pragma unroll
    for (int mi = 0; mi < 4; mi++)
      af[mi] = *(const s16x8*)&As[wd + mi * 16 + l15][quad * 8];
#pragma unroll
    for (int ni = 0; ni < 2; ni++)
      bq[ni] = *(const s16x8*)&Bs[wn + ni * 16 + l15][quad * 8];
#pragma unroll
    for (int mi = 0; mi < 4; mi++)
#pragma unroll
      for (int ni = 0; ni < 2; ni++)
        acc[mi][ni] = __builtin_amdgcn_mfma_f32_16x16x32_bf16(
            af[mi], bq[ni], acc[mi][ni], 0, 0, 0);
  }

  float* Wb = W + (size_t)b * D_ * Q_;
#pragma unroll
  for (int mi = 0; mi < 4; mi++)
#pragma unroll
    for (int ni = 0; ni < 2; ni++)
#pragma unroll
      for (int r = 0; r < 4; r++)
        Wb[(size_t)(wd + mi * 16 + quad * 4 + r) * Q_ + q0 + wn + ni * 16 +
           l15] = acc[mi][ni][r];
}

// ---------------------------------------------------------------------------
// d_out: [W (B*D*Q) | map (B*Q*L)]. K1 writes attn_q into the map region;
// K4 rewrites it in place as attn_c. Denominator partials pd (16 strips) +
// invd live in d_ws (2.2 MB). Fallback if ws is tiny: W-head (safe K1->K2;
// K4's early invd reads vs late W writes overlap only in theory — ws path
// avoids it entirely).
// ---------------------------------------------------------------------------
extern "C" void kernel_launch(void* const* d_in, const int* in_sizes, int n_in,
                              void* d_out, int out_size, void* d_ws,
                              size_t ws_size, hipStream_t stream) {
  const float* query = (const float*)d_in[0];
  const float* ctx = (const float*)d_in[1];
  float* W = (float*)d_out;
  float* attn = (float*)d_out + (size_t)B_ * D_ * Q_;

  const size_t need = (size_t)17 * B_ * Q_ * sizeof(float);
  float* pd = (ws_size >= need && d_ws) ? (float*)d_ws : W;
  float* invd = pd + (size_t)16 * B_ * Q_;

  k1_attnq<<<dim3(L_ / 64, B_), 256, 0, stream>>>(query, ctx, attn, pd);
  k2_invd<<<dim3(B_ * Q_ / 256), 256, 0, stream>>>(pd, invd);
  k4_weighted<<<dim3(Q_ / 64, B_), 256, 0, stream>>>(ctx, attn, invd, W);
}